// Round 1
// baseline (752.938 us; speedup 1.0000x reference)
//
#include <hip/hip_runtime.h>
#include <math.h>

// B=8, H=8, L=1024, E=512. rows = B*H*L = 65536, one wave per row.
// Block = 16 waves (1024 thr) covering 16 consecutive l of one (b,h).

#define NW 16
#define TOPK 6

__global__ __launch_bounds__(1024) void autoagg_kernel(
    const float* __restrict__ q, const float* __restrict__ k,
    const float* __restrict__ v, float* __restrict__ outV,
    float* __restrict__ outC) {
  const int tid  = threadIdx.x;
  const int lane = tid & 63;
  const int w    = tid >> 6;
  const int bid  = blockIdx.x;
  const int row  = bid * NW + w;                       // flat (b,h,l)
  const int rowU = __builtin_amdgcn_readfirstlane(row); // wave-uniform row
  const int b    = rowU >> 13;
  const int h    = (rowU >> 10) & 7;
  const int l0   = (bid & 63) * NW;

  const float* qrow = q + (size_t)rowU * 512;
  const float* krow = k + (size_t)rowU * 512;   // uniform base -> s_load path
  const float* vrow = v + (size_t)rowU * 512;

  // --- static per-lane q window: qw[x] = q[(8*lane + x) & 511], x in [0,24)
  float qw[24];
  const float4* q4 = (const float4*)qrow;
#pragma unroll
  for (int u = 0; u < 6; ++u) {
    float4 t = q4[(2 * lane + u) & 127];
    qw[4 * u + 0] = t.x; qw[4 * u + 1] = t.y;
    qw[4 * u + 2] = t.z; qw[4 * u + 3] = t.w;
  }

  // --- systolic circular correlation ---------------------------------------
  // step R: lane j holds acc chunk m = (j - 2R) & 63 (t = 8m + i).
  //   acc[i] += q[8j + i + c] * k[16R + c],  c in [0,16)   (q idx static!)
  // then rotate acc chunks +2 lanes.
  float acc[8] = {0.f,0.f,0.f,0.f,0.f,0.f,0.f,0.f};
  const int src = (lane - 2) & 63;
#pragma unroll 4
  for (int R = 0; R < 32; ++R) {
    float kc[16];
#pragma unroll
    for (int c = 0; c < 16; ++c) kc[c] = krow[16 * R + c];  // wave-uniform
#pragma unroll
    for (int c = 0; c < 16; ++c) {
#pragma unroll
      for (int i = 0; i < 8; ++i)
        acc[i] = fmaf(qw[i + c], kc[c], acc[i]);
    }
#pragma unroll
    for (int i = 0; i < 8; ++i) acc[i] = __shfl(acc[i], src, 64);
  }
  // 32 rotations * 2 lanes = 64 -> chunks are home: acc[i] = corr[row][8*lane+i]

  // --- top-6 across the wave (matches lax.top_k: larger value, lower index)
  float vals[8];
#pragma unroll
  for (int i = 0; i < 8; ++i) vals[i] = acc[i];
  float wts[TOPK]; int dly[TOPK];
#pragma unroll
  for (int it = 0; it < TOPK; ++it) {
    float m = vals[0]; int mi = 0;
#pragma unroll
    for (int i = 1; i < 8; ++i)
      if (vals[i] > m) { m = vals[i]; mi = i; }
    int gi = (lane << 3) | mi;
#pragma unroll
    for (int off = 32; off >= 1; off >>= 1) {
      float om = __shfl_xor(m, off, 64);
      int   oi = __shfl_xor(gi, off, 64);
      if (om > m || (om == m && oi < gi)) { m = om; gi = oi; }
    }
    wts[it] = m; dly[it] = gi;
    if ((gi >> 3) == lane) vals[gi & 7] = -INFINITY;
  }

  // --- softmax over the 6 weights (wts[0] is the max)
  float tw[TOPK]; float ssum = 0.f;
#pragma unroll
  for (int it = 0; it < TOPK; ++it) { tw[it] = expf(wts[it] - wts[0]); ssum += tw[it]; }
  const float inv = 1.f / ssum;
#pragma unroll
  for (int it = 0; it < TOPK; ++it) tw[it] *= inv;

  // --- V[t] = sum_k tw[k] * v[(t + d_k) & 511]
  float V[8] = {0.f,0.f,0.f,0.f,0.f,0.f,0.f,0.f};
#pragma unroll
  for (int it = 0; it < TOPK; ++it) {
    const int   d   = dly[it];
    const float twk = tw[it];
#pragma unroll
    for (int i = 0; i < 8; ++i)
      V[i] = fmaf(twk, vrow[((lane << 3) + i + d) & 511], V[i]);
  }
  float4* ov = (float4*)(outV + (size_t)rowU * 512 + (lane << 3));
  ov[0] = make_float4(V[0], V[1], V[2], V[3]);
  ov[1] = make_float4(V[4], V[5], V[6], V[7]);

  // --- transposed corr output via LDS tile: outC[b][e][h][l] = corr[b][h][l][e]
  __shared__ float tile[64][18];   // +2 pad: write stride 144B -> 2-way (free)
  for (int c = 0; c < 8; ++c) {    // e-chunk of 64
    __syncthreads();
    if ((lane >> 3) == c) {
      const int e0 = (lane & 7) << 3;
#pragma unroll
      for (int i = 0; i < 8; ++i) tile[e0 + i][w] = acc[i];
    }
    __syncthreads();
    const int de = tid >> 4;       // 0..63
    const int dl = tid & 15;       // 0..15  -> 64B contiguous stores
    outC[(((size_t)b * 512 + (c << 6) + de) * 8 + h) * 1024 + l0 + dl] =
        tile[de][dl];
  }
}

extern "C" void kernel_launch(void* const* d_in, const int* in_sizes, int n_in,
                              void* d_out, int out_size, void* d_ws, size_t ws_size,
                              hipStream_t stream) {
  const float* q = (const float*)d_in[0];
  const float* k = (const float*)d_in[1];
  const float* v = (const float*)d_in[2];
  float* outV = (float*)d_out;
  float* outC = (float*)d_out + (size_t)8 * 8 * 1024 * 512;  // after V
  dim3 grid(65536 / NW), block(NW * 64);
  hipLaunchKernelGGL(autoagg_kernel, grid, block, 0, stream, q, k, v, outV, outC);
}

// Round 2
// 628.570 us; speedup vs baseline: 1.1979x; 1.1979x over previous
//
#include <hip/hip_runtime.h>
#include <math.h>

// B=8, H=8, L=1024, E=512. One wave per row, 16 waves/block.
// corr = Re(IFFT(FFT(q) * conj(FFT(k)))) via z=q+ik packing (2 FFTs/row).

#define NW 16
#define TOPK 6

__device__ __forceinline__ float2 cmul(float2 a, float2 b) {
  return make_float2(fmaf(a.x, b.x, -(a.y * b.y)), fmaf(a.x, b.y, a.y * b.x));
}
__device__ __forceinline__ float2 cadd(float2 a, float2 b) { return make_float2(a.x + b.x, a.y + b.y); }
__device__ __forceinline__ float2 csub(float2 a, float2 b) { return make_float2(a.x - b.x, a.y - b.y); }
__device__ __forceinline__ float2 mnegi(float2 v) { return make_float2(v.y, -v.x); }  // * (-i)

struct Tw { float2 w512, t32, t16, t8, t4, t2; };

// In: y[m] = x[u + 64*m] (u = lane). Out: y[r] = X[8*rev6(u) + r], X = DFT_512(x).
__device__ __forceinline__ void fft512(float2 y[8], const Tw& T, int u) {
  // ---- lane-local radix-8 DFT over m (natural-order outputs s_r) ----
  float2 p0 = cadd(y[0], y[4]), p1 = csub(y[0], y[4]);
  float2 p2 = cadd(y[2], y[6]), p3 = csub(y[2], y[6]);
  float2 q0 = cadd(y[1], y[5]), q1 = csub(y[1], y[5]);
  float2 q2 = cadd(y[3], y[7]), q3 = csub(y[3], y[7]);
  float2 mp3 = mnegi(p3), mq3 = mnegi(q3);
  float2 E0 = cadd(p0, p2), E2 = csub(p0, p2);
  float2 E1 = cadd(p1, mp3), E3 = csub(p1, mp3);
  float2 O0 = cadd(q0, q2), O2 = csub(q0, q2);
  float2 O1 = cadd(q1, mq3), O3 = csub(q1, mq3);
  const float RT = 0.70710678118654752440f;
  float2 T1 = make_float2(RT * (O1.x + O1.y), RT * (O1.y - O1.x));   // O1*W8^1
  float2 T2 = mnegi(O2);                                             // O2*W8^2
  float2 T3 = make_float2(RT * (O3.y - O3.x), -RT * (O3.x + O3.y));  // O3*W8^3
  float2 s0 = cadd(E0, O0), s4 = csub(E0, O0);
  float2 s1 = cadd(E1, T1), s5 = csub(E1, T1);
  float2 s2 = cadd(E2, T2), s6 = csub(E2, T2);
  float2 s3 = cadd(E3, T3), s7 = csub(E3, T3);
  // ---- twiddle W512^{u*r} ----
  float2 wp = T.w512;
  y[0] = s0;
  y[1] = cmul(s1, wp);
  wp = cmul(wp, T.w512); y[2] = cmul(s2, wp);
  wp = cmul(wp, T.w512); y[3] = cmul(s3, wp);
  wp = cmul(wp, T.w512); y[4] = cmul(s4, wp);
  wp = cmul(wp, T.w512); y[5] = cmul(s5, wp);
  wp = cmul(wp, T.w512); y[6] = cmul(s6, wp);
  wp = cmul(wp, T.w512); y[7] = cmul(s7, wp);
  // ---- 64-point across-lane FFT: 6 radix-2 DIF stages via shfl_xor ----
#define XST(H, TWX, TWY)                                     \
  _Pragma("unroll") for (int r = 0; r < 8; ++r) {            \
    float ox = __shfl_xor(y[r].x, H, 64);                    \
    float oy = __shfl_xor(y[r].y, H, 64);                    \
    float sx = y[r].x + ox, sy = y[r].y + oy;                \
    float dx = ox - y[r].x, dy = oy - y[r].y;                \
    float bx = fmaf(dx, TWX, -(dy * (TWY)));                 \
    float by = fmaf(dx, TWY, dy * (TWX));                    \
    bool lo = (u & H) == 0;                                  \
    y[r].x = lo ? sx : bx;                                   \
    y[r].y = lo ? sy : by;                                   \
  }
  XST(32, T.t32.x, T.t32.y)
  XST(16, T.t16.x, T.t16.y)
  XST(8,  T.t8.x,  T.t8.y)
  XST(4,  T.t4.x,  T.t4.y)
  XST(2,  T.t2.x,  T.t2.y)
#undef XST
#pragma unroll
  for (int r = 0; r < 8; ++r) {  // H=1, tw=1
    float ox = __shfl_xor(y[r].x, 1, 64);
    float oy = __shfl_xor(y[r].y, 1, 64);
    bool lo = (u & 1) == 0;
    y[r].x = lo ? (y[r].x + ox) : (ox - y[r].x);
    y[r].y = lo ? (y[r].y + oy) : (oy - y[r].y);
  }
}

__device__ __forceinline__ int swz(int f) {  // LDS anti-bank-conflict swizzle
  return f ^ ((f >> 3) & 7) ^ ((f >> 6) & 7);
}

__global__ __launch_bounds__(1024) void autoagg_kernel(
    const float* __restrict__ q, const float* __restrict__ k,
    const float* __restrict__ v, float* __restrict__ outV,
    float* __restrict__ outC) {
  __shared__ float2 zbuf[NW * 512];  // 64 KB; re-used as corrT tile later
  const int tid = threadIdx.x;
  const int u   = tid & 63;
  const int w   = tid >> 6;
  const int bid = blockIdx.x;
  const int row  = bid * NW + w;
  const int rowU = __builtin_amdgcn_readfirstlane(row);
  const int b  = rowU >> 13;
  const int h  = (rowU >> 10) & 7;
  const int l0 = (bid & 63) * NW;

  const float* qrow = q + (size_t)rowU * 512;
  const float* krow = k + (size_t)rowU * 512;
  const float* vrow = v + (size_t)rowU * 512;

  // rev6(u) and per-lane twiddles
  const int rl = ((u & 1) << 5) | ((u & 2) << 3) | ((u & 4) << 1) |
                 ((u & 8) >> 1) | ((u & 16) >> 3) | ((u & 32) >> 5);
  const float N2PI = -6.28318530717958647692f;
  Tw T; float s_, c_;
  __sincosf(N2PI * (float)u        * (1.f / 512.f), &s_, &c_); T.w512 = make_float2(c_, s_);
  __sincosf(N2PI * (float)(u & 31) * (1.f / 64.f),  &s_, &c_); T.t32  = make_float2(c_, s_);
  __sincosf(N2PI * (float)(u & 15) * (1.f / 32.f),  &s_, &c_); T.t16  = make_float2(c_, s_);
  __sincosf(N2PI * (float)(u & 7)  * (1.f / 16.f),  &s_, &c_); T.t8   = make_float2(c_, s_);
  __sincosf(N2PI * (float)(u & 3)  * (1.f / 8.f),   &s_, &c_); T.t4   = make_float2(c_, s_);
  T.t2 = (u & 1) ? make_float2(0.f, -1.f) : make_float2(1.f, 0.f);

  // ---- FFT1: z = q + i*k ----
  float2 y[8];
#pragma unroll
  for (int m = 0; m < 8; ++m)
    y[m] = make_float2(qrow[u + (m << 6)], krow[u + (m << 6)]);
  fft512(y, T, u);

  // ---- store Z[f] to LDS (f = 8*rl + r), swizzled ----
  const int woff = w << 9;
#pragma unroll
  for (int r = 0; r < 8; ++r) zbuf[woff + swz((rl << 3) | r)] = y[r];
  __syncthreads();

  // ---- Hermitian separation + pointwise: input2[f] = conj(Q*conj(K))/2048 ----
  const float SCL = 1.f / 2048.f;  // (1/4 from separation) * (1/512 inverse)
  float2 a2[8];
#pragma unroll
  for (int m = 0; m < 8; ++m) {
    int fA = (m << 6) | u;
    int fB = (512 - fA) & 511;
    float2 A  = zbuf[woff + swz(fA)];
    float2 Bv = zbuf[woff + swz(fB)];
    float sx = A.x + Bv.x, sy = A.y - Bv.y;   // A + conj(B) = 2Q
    float dx = A.x - Bv.x, dy = A.y + Bv.y;   // A - conj(B) = 2iK
    a2[m] = make_float2((sx * dy - sy * dx) * SCL,
                        -fmaf(sx, dx, sy * dy) * SCL);
  }

  // ---- FFT2: corr[8*rl + r] = Re(out[r]) ----
  fft512(a2, T, u);
  float corrv[8];
#pragma unroll
  for (int r = 0; r < 8; ++r) corrv[r] = a2[r].x;

  // ---- top-6 across wave (larger value, then lower index) ----
  float vals[8];
#pragma unroll
  for (int r = 0; r < 8; ++r) vals[r] = corrv[r];
  float wts[TOPK]; int dly[TOPK];
#pragma unroll
  for (int it = 0; it < TOPK; ++it) {
    float m = vals[0]; int mi = 0;
#pragma unroll
    for (int i = 1; i < 8; ++i)
      if (vals[i] > m) { m = vals[i]; mi = i; }
    int gi = (rl << 3) | mi;
#pragma unroll
    for (int off = 32; off >= 1; off >>= 1) {
      float om = __shfl_xor(m, off, 64);
      int   oi = __shfl_xor(gi, off, 64);
      if (om > m || (om == m && oi < gi)) { m = om; gi = oi; }
    }
    wts[it] = m; dly[it] = gi;
#pragma unroll
    for (int i = 0; i < 8; ++i)
      vals[i] = (gi == ((rl << 3) | i)) ? -INFINITY : vals[i];
  }

  // ---- softmax over the 6 weights ----
  float tw[TOPK]; float ssum = 0.f;
#pragma unroll
  for (int it = 0; it < TOPK; ++it) { tw[it] = __expf(wts[it] - wts[0]); ssum += tw[it]; }
  const float inv = 1.f / ssum;
#pragma unroll
  for (int it = 0; it < TOPK; ++it) tw[it] *= inv;

  // ---- V[t] = sum_k tw[k] * v[(t + d_k) & 511], t = 8*rl + i ----
  float V[8] = {0.f, 0.f, 0.f, 0.f, 0.f, 0.f, 0.f, 0.f};
#pragma unroll
  for (int it = 0; it < TOPK; ++it) {
    const int   d   = dly[it];
    const float twk = tw[it];
#pragma unroll
    for (int i = 0; i < 8; ++i)
      V[i] = fmaf(twk, vrow[((rl << 3) + i + d) & 511], V[i]);
  }
  float4* ov = (float4*)(outV + (size_t)rowU * 512 + (rl << 3));
  ov[0] = make_float4(V[0], V[1], V[2], V[3]);
  ov[1] = make_float4(V[4], V[5], V[6], V[7]);

  // ---- transposed corr: outC[b][e][h][l], via LDS tile (aliases zbuf) ----
  float* tileF = (float*)zbuf;
  for (int c = 0; c < 8; ++c) {
    __syncthreads();
    if ((rl >> 3) == c) {
      const int e0 = (rl & 7) << 3;
#pragma unroll
      for (int i = 0; i < 8; ++i) tileF[(e0 + i) * 18 + w] = corrv[i];
    }
    __syncthreads();
    const int de = tid >> 4;  // 0..63
    const int dl = tid & 15;  // 0..15 -> 64B contiguous stores
    outC[(((size_t)b * 512 + (c << 6) + de) * 8 + h) * 1024 + l0 + dl] =
        tileF[de * 18 + dl];
  }
}

extern "C" void kernel_launch(void* const* d_in, const int* in_sizes, int n_in,
                              void* d_out, int out_size, void* d_ws, size_t ws_size,
                              hipStream_t stream) {
  const float* q = (const float*)d_in[0];
  const float* k = (const float*)d_in[1];
  const float* v = (const float*)d_in[2];
  float* outV = (float*)d_out;
  float* outC = (float*)d_out + (size_t)8 * 8 * 1024 * 512;
  dim3 grid(65536 / NW), block(NW * 64);
  hipLaunchKernelGGL(autoagg_kernel, grid, block, 0, stream, q, k, v, outV, outC);
}

// Round 3
// 461.836 us; speedup vs baseline: 1.6303x; 1.3610x over previous
//
#include <hip/hip_runtime.h>
#include <math.h>

// B=8, H=8, L=1024, E=512. Wave = 2 rows (sequential); block = 8 waves = 16 l's.
// corr = Re(IFFT(FFT(q)*conj(FFT(k)))) via z=q+ik packing; FFT512 = radix-8^3
// with two wave-private padded-LDS transposes (no block barriers in FFT).

#define TOPK 6
#define LGKM0 asm volatile("s_waitcnt lgkmcnt(0)" ::: "memory")

__device__ __forceinline__ float2 cmul(float2 a, float2 b) {
  return make_float2(fmaf(a.x, b.x, -(a.y * b.y)), fmaf(a.x, b.y, a.y * b.x));
}
__device__ __forceinline__ float2 cadd(float2 a, float2 b) { return make_float2(a.x + b.x, a.y + b.y); }
__device__ __forceinline__ float2 csub(float2 a, float2 b) { return make_float2(a.x - b.x, a.y - b.y); }
__device__ __forceinline__ float2 mnegi(float2 v) { return make_float2(v.y, -v.x); }  // * (-i)

// out[r] = sum_m in[m] * W8^{m*r}   (verified in production rounds 1-2)
__device__ __forceinline__ void radix8(float2 y[8]) {
  float2 p0 = cadd(y[0], y[4]), p1 = csub(y[0], y[4]);
  float2 p2 = cadd(y[2], y[6]), p3 = csub(y[2], y[6]);
  float2 q0 = cadd(y[1], y[5]), q1 = csub(y[1], y[5]);
  float2 q2 = cadd(y[3], y[7]), q3 = csub(y[3], y[7]);
  float2 mp3 = mnegi(p3), mq3 = mnegi(q3);
  float2 E0 = cadd(p0, p2), E2 = csub(p0, p2);
  float2 E1 = cadd(p1, mp3), E3 = csub(p1, mp3);
  float2 O0 = cadd(q0, q2), O2 = csub(q0, q2);
  float2 O1 = cadd(q1, mq3), O3 = csub(q1, mq3);
  const float RT = 0.70710678118654752440f;
  float2 T1 = make_float2(RT * (O1.x + O1.y), RT * (O1.y - O1.x));   // *W8^1
  float2 T2 = mnegi(O2);                                             // *W8^2
  float2 T3 = make_float2(RT * (O3.y - O3.x), -RT * (O3.x + O3.y));  // *W8^3
  y[0] = cadd(E0, O0); y[4] = csub(E0, O0);
  y[1] = cadd(E1, T1); y[5] = csub(E1, T1);
  y[2] = cadd(E2, T2); y[6] = csub(E2, T2);
  y[3] = cadd(E3, T3); y[7] = csub(E3, T3);
}

__device__ __forceinline__ void twiddle8(float2 y[8], float2 w) {
  float2 wp = w;
  y[1] = cmul(y[1], wp);
  wp = cmul(wp, w); y[2] = cmul(y[2], wp);
  wp = cmul(wp, w); y[3] = cmul(y[3], wp);
  wp = cmul(wp, w); y[4] = cmul(y[4], wp);
  wp = cmul(wp, w); y[5] = cmul(y[5], wp);
  wp = cmul(wp, w); y[6] = cmul(y[6], wp);
  wp = cmul(wp, w); y[7] = cmul(y[7], wp);
}

// In: y[m] = x[64m + u]. Out: y[r] = X[(u>>3) + 8*(u&7) + 64*r].
// zx/zy: 576-float wave-private LDS scratch each. All transposes 2-lanes/bank.
__device__ __forceinline__ void fft512t(float2 y[8], float* zx, float* zy,
                                        int u, float2 w512u, float2 w64n0) {
  const int f0 = u >> 3, n0 = u & 7;
  radix8(y);              // digit f0, twiddle W512^{u*f0}
  twiddle8(y, w512u);
#pragma unroll
  for (int r = 0; r < 8; ++r) { int s = 72 * r + u; zx[s] = y[r].x; zy[s] = y[r].y; }
  LGKM0;
#pragma unroll
  for (int j = 0; j < 8; ++j) {
    int s = 72 * f0 + 8 * j + n0;
    y[j] = make_float2(zx[s], zy[s]);
  }
  radix8(y);              // digit g0, twiddle W64^{n0*g0}
  twiddle8(y, w64n0);
  LGKM0;
#pragma unroll
  for (int g = 0; g < 8; ++g) {
    int s = 72 * f0 + 8 * g + (n0 ^ g);
    zx[s] = y[g].x; zy[s] = y[g].y;
  }
  LGKM0;
#pragma unroll
  for (int j = 0; j < 8; ++j) {
    int s = 72 * f0 + 8 * n0 + (j ^ n0);
    y[j] = make_float2(zx[s], zy[s]);
  }
  radix8(y);              // digit g1, no twiddle
}

__global__ __launch_bounds__(512, 8) void autoagg_kernel(
    const float* __restrict__ q, const float* __restrict__ kk,
    const float* __restrict__ v, float* __restrict__ outV,
    float* __restrict__ outC) {
  __shared__ float lds[9728];  // 8 waves x (2 x 576) z-scratch; aliased as 512x19 tile
  const int tid = threadIdx.x;
  const int u = tid & 63;
  const int w = tid >> 6;
  const int bid = blockIdx.x;
  float* zx = lds + w * 1152;
  float* zy = zx + 576;

  const int f0 = u >> 3, n0 = u & 7;
  const int base = f0 + (n0 << 3);  // corr index of reg r is base + 64r

  const float N2PI = -6.28318530717958647692f;
  float s_, c_;
  __sincosf(N2PI * (float)u * (1.f / 512.f), &s_, &c_);
  const float2 w512u = make_float2(c_, s_);
  __sincosf(N2PI * (float)n0 * (1.f / 64.f), &s_, &c_);
  const float2 w64n0 = make_float2(c_, s_);

  float2 y[8];
  float cA[8];  // row-A corr held across row-B processing

#pragma unroll
  for (int p = 0; p < 2; ++p) {
    const int row = ((bid << 4) | (p << 3)) + w;
    const int rowU = __builtin_amdgcn_readfirstlane(row);
    const float* qrow = q + (size_t)rowU * 512;
    const float* krow = kk + (size_t)rowU * 512;
    const float* vrow = v + (size_t)rowU * 512;

#pragma unroll
    for (int m = 0; m < 8; ++m)
      y[m] = make_float2(qrow[u + (m << 6)], krow[u + (m << 6)]);

    fft512t(y, zx, zy, u, w512u, w64n0);  // Z at index (u>>3)+8(u&7)+64r

    // store Z at sigma3(f) = 72*(f>>6) + 8*((f>>3)&7) + (f&7)
    LGKM0;
#pragma unroll
    for (int r = 0; r < 8; ++r) {
      int s = 72 * r + (n0 << 3) + f0;
      zx[s] = y[r].x; zy[s] = y[r].y;
    }
    LGKM0;
    // Hermitian separation + pointwise product (verified math from round 2)
    const float SCL = 1.f / 2048.f;
#pragma unroll
    for (int m = 0; m < 8; ++m) {
      int fA = (m << 6) | u;
      int fB = (512 - fA) & 511;
      int sA = 72 * m + (f0 << 3) + n0;
      int sB = 72 * (fB >> 6) + (((fB >> 3) & 7) << 3) + (fB & 7);
      float Ax = zx[sA], Ay = zy[sA];
      float Bx = zx[sB], By = zy[sB];
      float sx = Ax + Bx, sy = Ay - By;   // 2Q
      float dx = Ax - Bx, dy = Ay + By;   // 2iK
      y[m] = make_float2((sx * dy - sy * dx) * SCL,
                         -fmaf(sx, dx, sy * dy) * SCL);
    }

    fft512t(y, zx, zy, u, w512u, w64n0);  // corr[base+64r] = y[r].x

    // ---- top-6: packed key = (monotone value bits & ~0x1FF) | (511 - idx)
    unsigned key[8];
#pragma unroll
    for (int r = 0; r < 8; ++r) {
      unsigned bb = __float_as_uint(y[r].x);
      unsigned sgn = (unsigned)((int)bb >> 31);
      unsigned mono = bb ^ (sgn | 0x80000000u);
      key[r] = (mono & 0xFFFFFE00u) | (unsigned)(511 - (base + (r << 6)));
    }
    float w0 = 0.f, tw[TOPK]; int dly[TOPK];
#pragma unroll
    for (int it = 0; it < TOPK; ++it) {
      unsigned kmax = key[0];
#pragma unroll
      for (int i = 1; i < 8; ++i) kmax = key[i] > kmax ? key[i] : kmax;
#pragma unroll
      for (int off = 32; off >= 1; off >>= 1) {
        unsigned o = (unsigned)__shfl_xor((int)kmax, off, 64);
        kmax = o > kmax ? o : kmax;
      }
      unsigned mb = kmax & 0xFFFFFE00u;
      unsigned vb = (mb & 0x80000000u) ? (mb ^ 0x80000000u) : ~mb;
      float val = __uint_as_float(vb);
      if (it == 0) w0 = val;
      tw[it] = __expf(val - w0);
      dly[it] = 511 - (int)(kmax & 0x1FFu);
#pragma unroll
      for (int i = 0; i < 8; ++i) if (key[i] == kmax) key[i] = 0u;
    }
    float ssum = 0.f;
#pragma unroll
    for (int it = 0; it < TOPK; ++it) ssum += tw[it];
    const float inv = 1.f / ssum;

    // ---- V[t] = sum_k w_k * v[(t + d_k) & 511], t = base + 64i
    float V[8] = {0.f, 0.f, 0.f, 0.f, 0.f, 0.f, 0.f, 0.f};
#pragma unroll
    for (int it = 0; it < TOPK; ++it) {
      const float twk = tw[it] * inv;
      const int d = dly[it];
#pragma unroll
      for (int i = 0; i < 8; ++i)
        V[i] = fmaf(twk, vrow[(base + (i << 6) + d) & 511], V[i]);
    }
    float* ovr = outV + (size_t)rowU * 512;
#pragma unroll
    for (int i = 0; i < 8; ++i) ovr[base + (i << 6)] = V[i];

    if (p == 0) {
#pragma unroll
      for (int r = 0; r < 8; ++r) cA[r] = y[r].x;
    }
  }

  // ---- transposed corr via block tile [512 e][19 pad], 16 l's -> 64B stores
  __syncthreads();
#pragma unroll
  for (int r = 0; r < 8; ++r) {
    int e = base + (r << 6);
    lds[e * 19 + w] = cA[r];
    lds[e * 19 + w + 8] = y[r].x;
  }
  __syncthreads();
  const int b9 = bid >> 9;
  const int h9 = (bid >> 6) & 7;
  const int l0 = (bid & 63) << 4;
  const int de = tid >> 4;  // 0..31
  const int dl = tid & 15;  // 0..15 -> 64B contiguous stores
#pragma unroll
  for (int c = 0; c < 16; ++c) {
    int e = (c << 5) + de;
    outC[(((size_t)b9 * 512 + e) * 8 + h9) * 1024 + l0 + dl] = lds[e * 19 + dl];
  }
}

extern "C" void kernel_launch(void* const* d_in, const int* in_sizes, int n_in,
                              void* d_out, int out_size, void* d_ws, size_t ws_size,
                              hipStream_t stream) {
  const float* q = (const float*)d_in[0];
  const float* k = (const float*)d_in[1];
  const float* v = (const float*)d_in[2];
  float* outV = (float*)d_out;
  float* outC = (float*)d_out + (size_t)8 * 8 * 1024 * 512;
  dim3 grid(65536 / 16), block(512);
  hipLaunchKernelGGL(autoagg_kernel, grid, block, 0, stream, q, k, v, outV, outC);
}